// Round 7
// baseline (295.577 us; speedup 1.0000x reference)
//
#include <hip/hip_runtime.h>
#include <stdint.h>

// Problem constants (fixed by setup_inputs: B=16, A=9, H=W=192)
#define A_NUM    9
#define W_FEAT   192
#define H_FEAT   192
#define K_FEAT   (W_FEAT * H_FEAT)     // 36864 positions
#define N_ANCH   (K_FEAT * A_NUM)      // 331776 anchors per batch
#define BATCH    16
#define PRE_NMS  6000
#define POST_NMS 300
#define CAP      8192                  // full candidate buffer (above tbin)
#define CHUNK    4096                  // elements per block for hist/compact
#define BPB      (N_ANCH / CHUNK)      // 81 blocks per batch
#define CPA      (K_FEAT / CHUNK)      // 9 chunks per anchor-plane
#define SBUF_CAP 1024                  // per-block candidate staging (mean ~91)
#define T2TGT    700                   // fast-path candidate target
#define SORT2    2048                  // fast-path sort size (m2 <= ~2000)
#define NWORD    (SORT2 / 64)          // 32 mask words per row
#define ZERO_WORDS (2 * BATCH * 256 + BATCH * 32)   // histA + histB + cntpad

// py-faster-rcnn standard anchors (base 16, ratios .5/1/2, scales 8/16/32)
__constant__ float c_anchors[A_NUM][4] = {
    { -84.f,  -40.f,  99.f,  55.f},
    {-176.f,  -88.f, 191.f, 103.f},
    {-360.f, -184.f, 375.f, 199.f},
    { -56.f,  -56.f,  71.f,  71.f},
    {-120.f, -120.f, 135.f, 135.f},
    {-248.f, -248.f, 263.f, 263.f},
    { -36.f,  -80.f,  51.f,  95.f},
    { -80.f, -168.f,  95.f, 183.f},
    {-168.f, -344.f, 183.f, 359.f},
};

__device__ __forceinline__ unsigned key_bits(float s) {
    unsigned ub = __float_as_uint(s);
    return (ub & 0x80000000u) ? ~ub : (ub | 0x80000000u);
}

__device__ __forceinline__ const float* chunk_ptr(const float* scores, int blk,
                                                  int& b, int& a, int& koff) {
    b = blk / BPB;
    int chunk = blk - b * BPB;
    a = chunk / CPA;
    koff = (chunk - a * CPA) * CHUNK;
    return scores + ((size_t)(b * 2 * A_NUM + A_NUM + a)) * K_FEAT + koff;
}

// ballot-aggregated LDS histogram add: one atomic per distinct bin per wave
__device__ __forceinline__ void hist_add(unsigned* lh, unsigned bin) {
    unsigned long long peers = __ballot(1);
    #pragma unroll
    for (int bit = 0; bit < 8; ++bit) {
        unsigned long long vote = __ballot((bin >> bit) & 1);
        peers &= ((bin >> bit) & 1) ? vote : ~vote;
    }
    int lane = threadIdx.x & 63;
    if (lane == (int)(__ffsll((long long)peers) - 1))
        atomicAdd(&lh[bin], (unsigned)__popcll(peers));
}

__device__ __forceinline__ float4 decode_box(unsigned n, const float* __restrict__ deltas,
                                             int b, float wmax, float hmax) {
    unsigned kk = n / A_NUM, a = n - kk * A_NUM;
    unsigned hh = kk / W_FEAT, ww = kk - hh * W_FEAT;
    size_t dbase = ((size_t)(b * 4 * A_NUM + 4 * a)) * K_FEAT + kk;
    float dx = deltas[dbase];
    float dy = deltas[dbase + (size_t)K_FEAT];
    float dw = deltas[dbase + (size_t)2 * K_FEAT];
    float dh = deltas[dbase + (size_t)3 * K_FEAT];
    float ax1 = c_anchors[a][0] + ww * 16.0f;
    float ay1 = c_anchors[a][1] + hh * 16.0f;
    float ax2 = c_anchors[a][2] + ww * 16.0f;
    float ay2 = c_anchors[a][3] + hh * 16.0f;
    float waf = ax2 - ax1 + 1.0f, haf = ay2 - ay1 + 1.0f;
    float cx = ax1 + 0.5f * waf, cy = ay1 + 0.5f * haf;
    float pcx = dx * waf + cx, pcy = dy * haf + cy;
    float pw = expf(dw) * waf, ph = expf(dh) * haf;
    float4 box;
    box.x = fminf(fmaxf(pcx - 0.5f * pw, 0.f), wmax);
    box.y = fminf(fmaxf(pcy - 0.5f * ph, 0.f), hmax);
    box.z = fminf(fmaxf(pcx + 0.5f * pw, 0.f), wmax);
    box.w = fminf(fmaxf(pcy + 0.5f * ph, 0.f), hmax);
    return box;
}

// IoU(a, c) > 0.7 — identical algebra in every consumer (bit-identical decisions)
__device__ __forceinline__ bool iou_over(float4 a, float aa, float4 c, float ca) {
    float xx1 = fmaxf(a.x, c.x), yy1 = fmaxf(a.y, c.y);
    float xx2 = fminf(a.z, c.z), yy2 = fminf(a.w, c.w);
    float iw = fmaxf(xx2 - xx1 + 1.f, 0.f);
    float ih = fmaxf(yy2 - yy1 + 1.f, 0.f);
    float inter = iw * ih;
    return inter > 0.7f * (aa + ca - inter);
}

// --- Pass 0: zero hist/cnt workspace (replaces pathological hipMemsetAsync) --
__global__ __launch_bounds__(256) void init_kernel(unsigned* __restrict__ p) {
    p[blockIdx.x * 256 + threadIdx.x] = 0u;
}

// --- Pass 1a: per-batch 256-bin histogram of top-8 key bits ------------------
__global__ __launch_bounds__(256) void histA_kernel(const float* __restrict__ scores,
                                                    unsigned* __restrict__ histA) {
    __shared__ unsigned lh[256];
    int tid = threadIdx.x;
    lh[tid] = 0;
    __syncthreads();
    int b, a, koff;
    const float* p = chunk_ptr(scores, blockIdx.x, b, a, koff);
    const float4* p4 = (const float4*)p;
    #pragma unroll
    for (int it = 0; it < CHUNK / 1024; ++it) {
        float4 v = p4[it * 256 + tid];
        hist_add(lh, key_bits(v.x) >> 24);
        hist_add(lh, key_bits(v.y) >> 24);
        hist_add(lh, key_bits(v.z) >> 24);
        hist_add(lh, key_bits(v.w) >> 24);
    }
    __syncthreads();
    if (lh[tid]) atomicAdd(&histA[b * 256 + tid], lh[tid]);
}

// --- Pass 1b: top-8 threshold digit ------------------------------------------
__global__ void scanA_kernel(const unsigned* __restrict__ histA,
                             unsigned* __restrict__ d8,
                             unsigned* __restrict__ aboveA) {
    int b = blockIdx.x;
    __shared__ unsigned h[256];
    h[threadIdx.x] = histA[b * 256 + threadIdx.x];
    __syncthreads();
    if (threadIdx.x == 0) {
        unsigned acc = 0; int d = 0;
        for (int i = 255; i >= 0; --i) {
            unsigned v = h[i];
            if (acc + v >= PRE_NMS) { d = i; break; }
            acc += v;
        }
        d8[b] = (unsigned)d;
        aboveA[b] = acc;
    }
}

// --- Pass 2a: refine next 8 bits among values with top-8 == d8 ---------------
__global__ __launch_bounds__(256) void histB_kernel(const float* __restrict__ scores,
                                                    const unsigned* __restrict__ d8,
                                                    unsigned* __restrict__ histB) {
    __shared__ unsigned lh[256];
    int tid = threadIdx.x;
    lh[tid] = 0;
    __syncthreads();
    int b, a, koff;
    const float* p = chunk_ptr(scores, blockIdx.x, b, a, koff);
    unsigned d = d8[b];
    const float4* p4 = (const float4*)p;
    #pragma unroll
    for (int it = 0; it < CHUNK / 1024; ++it) {
        float4 v = p4[it * 256 + tid];
        unsigned u0 = key_bits(v.x), u1 = key_bits(v.y);
        unsigned u2 = key_bits(v.z), u3 = key_bits(v.w);
        if ((u0 >> 24) == d) hist_add(lh, (u0 >> 16) & 0xFF);
        if ((u1 >> 24) == d) hist_add(lh, (u1 >> 16) & 0xFF);
        if ((u2 >> 24) == d) hist_add(lh, (u2 >> 16) & 0xFF);
        if ((u3 >> 24) == d) hist_add(lh, (u3 >> 16) & 0xFF);
    }
    __syncthreads();
    if (lh[tid]) atomicAdd(&histB[b * 256 + tid], lh[tid]);
}

// --- Pass 2b: final 16-bit thresholds (6000-target and fast 700-target) ------
__global__ void scanB_kernel(const unsigned* __restrict__ histB,
                             const unsigned* __restrict__ d8,
                             const unsigned* __restrict__ aboveA,
                             unsigned* __restrict__ tbin,
                             unsigned* __restrict__ tbin2) {
    int b = blockIdx.x;
    __shared__ unsigned h[256];
    h[threadIdx.x] = histB[b * 256 + threadIdx.x];
    __syncthreads();
    if (threadIdx.x == 0) {
        unsigned dd = d8[b];
        unsigned acc = aboveA[b];
        unsigned t2 = 0; bool t2set = false;
        if (acc >= T2TGT) { t2 = (dd + 1) << 8; t2set = true; }
        int d = 0;
        for (int i = 255; i >= 0; --i) {
            unsigned v = h[i];
            if (!t2set && acc + v >= T2TGT) { t2 = (dd << 8) | (unsigned)i; t2set = true; }
            if (acc + v >= PRE_NMS) { d = i; break; }
            acc += v;
        }
        tbin[b] = (dd << 8) | (unsigned)d;
        tbin2[b] = t2set ? t2 : ((dd << 8) | (unsigned)d);
    }
}

// --- Pass 3: compact candidates >= tbin (LDS staged, 1 global atomic/block) --
__global__ __launch_bounds__(256) void compact_kernel(
        const float* __restrict__ scores,
        const unsigned* __restrict__ tbin,
        unsigned* __restrict__ cntpad,
        unsigned long long* __restrict__ cand) {
    __shared__ unsigned long long sbuf[SBUF_CAP];
    __shared__ unsigned scount, sbase;
    int tid = threadIdx.x;
    if (tid == 0) scount = 0;
    __syncthreads();
    int b, a, koff;
    const float* p = chunk_ptr(scores, blockIdx.x, b, a, koff);
    unsigned t = tbin[b];
    const float4* p4 = (const float4*)p;
    #pragma unroll
    for (int it = 0; it < CHUNK / 1024; ++it) {
        float4 v = p4[it * 256 + tid];
        unsigned e0 = (unsigned)(koff + (it * 256 + tid) * 4);
        float vv[4] = {v.x, v.y, v.z, v.w};
        #pragma unroll
        for (int j = 0; j < 4; ++j) {
            unsigned ub = key_bits(vv[j]);
            if ((ub >> 16) >= t) {
                unsigned n = (e0 + j) * A_NUM + a;
                unsigned pos = atomicAdd(&scount, 1u);
                if (pos < SBUF_CAP)
                    sbuf[pos] = ((unsigned long long)ub << 32) | (unsigned)(~n);
            }
        }
    }
    __syncthreads();
    unsigned c = scount < SBUF_CAP ? scount : SBUF_CAP;
    if (tid == 0) sbase = atomicAdd(&cntpad[b << 5], c);
    __syncthreads();
    unsigned gb = sbase;
    for (unsigned i = tid; i < c; i += 256) {
        unsigned pos = gb + i;
        if (pos < CAP) cand[(size_t)b * CAP + pos] = sbuf[i];
    }
}

// --- Pass 4: filter >= tbin2, O(m^2) RANK sort (broadcast reads), decode -----
// Keys are distinct (index embedded) -> rank(i) = #{j : key_j > key_i} is an
// exact permutation. 4 j-quarters x 128 threads; candidate keys live in
// registers (compile-time-unrolled 4-slot groups, wave-uniform m2 gates).
__global__ __launch_bounds__(512) void sort_kernel(
        const unsigned long long* __restrict__ cand,
        const unsigned* __restrict__ cntpad,
        const unsigned* __restrict__ tbin2,
        const float* __restrict__ deltas,
        const float* __restrict__ im_info,
        float4* __restrict__ bxg,
        unsigned* __restrict__ m2arr,
        unsigned* __restrict__ okarr) {
    int b = blockIdx.x;
    __shared__ unsigned khi[SORT2];   // 8 KB
    __shared__ unsigned klo[SORT2];   // 8 KB
    __shared__ unsigned rnk[SORT2];   // 8 KB
    __shared__ unsigned lcnt;
    int tid = threadIdx.x;
    if (tid == 0) lcnt = 0;
    for (int i = tid; i < SORT2; i += 512) rnk[i] = 0u;
    __syncthreads();

    unsigned m = cntpad[b << 5];
    if (m > CAP) m = CAP;
    unsigned t2 = tbin2[b];
    for (unsigned i = tid; i < m; i += 512) {
        unsigned long long k64 = cand[(size_t)b * CAP + i];
        if ((unsigned)(k64 >> 48) >= t2) {
            unsigned pos = atomicAdd(&lcnt, 1u);
            if (pos < SORT2) {
                khi[pos] = (unsigned)(k64 >> 32);
                klo[pos] = (unsigned)k64;
            }
        }
    }
    __syncthreads();
    unsigned raw2 = lcnt;
    bool ok = (raw2 <= SORT2);
    unsigned m2 = raw2 > SORT2 ? SORT2 : raw2;

    if (ok && m2 > 0) {
        int q = tid >> 7, c = tid & 127;
        int jbeg = (int)((m2 * (unsigned)q) >> 2);
        int jend = (int)((m2 * (unsigned)(q + 1)) >> 2);

        #define LKEY(H, L, I) do { int _i = (I); \
            if (_i < (int)m2) { H = khi[_i]; L = klo[_i]; } \
            else { H = 0u; L = 0u; } } while (0)
        unsigned hA0, lA0, hA1, lA1, hA2, lA2, hA3, lA3;
        unsigned hB0, lB0, hB1, lB1, hB2, lB2, hB3, lB3;
        unsigned hC0, lC0, hC1, lC1, hC2, lC2, hC3, lC3;
        unsigned hD0, lD0, hD1, lD1, hD2, lD2, hD3, lD3;
        int rA0 = 0, rA1 = 0, rA2 = 0, rA3 = 0;
        int rB0 = 0, rB1 = 0, rB2 = 0, rB3 = 0;
        int rC0 = 0, rC1 = 0, rC2 = 0, rC3 = 0;
        int rD0 = 0, rD1 = 0, rD2 = 0, rD3 = 0;
        LKEY(hA0, lA0, c);        LKEY(hA1, lA1, c + 128);
        LKEY(hA2, lA2, c + 256);  LKEY(hA3, lA3, c + 384);
        bool gB = (c + 512  < (int)m2);
        bool gC = (c + 1024 < (int)m2);
        bool gD = (c + 1536 < (int)m2);
        if (gB) { LKEY(hB0, lB0, c + 512);  LKEY(hB1, lB1, c + 640);
                  LKEY(hB2, lB2, c + 768);  LKEY(hB3, lB3, c + 896); }
        if (gC) { LKEY(hC0, lC0, c + 1024); LKEY(hC1, lC1, c + 1152);
                  LKEY(hC2, lC2, c + 1280); LKEY(hC3, lC3, c + 1408); }
        if (gD) { LKEY(hD0, lD0, c + 1536); LKEY(hD1, lD1, c + 1664);
                  LKEY(hD2, lD2, c + 1792); LKEY(hD3, lD3, c + 1920); }

        #define KGT(H, L) (int)((hj > (H)) || ((hj == (H)) && (lj > (L))))
        for (int j = jbeg; j < jend; ++j) {
            unsigned hj = khi[j], lj = klo[j];   // wave-uniform broadcast
            rA0 += KGT(hA0, lA0); rA1 += KGT(hA1, lA1);
            rA2 += KGT(hA2, lA2); rA3 += KGT(hA3, lA3);
            if (gB) { rB0 += KGT(hB0, lB0); rB1 += KGT(hB1, lB1);
                      rB2 += KGT(hB2, lB2); rB3 += KGT(hB3, lB3); }
            if (gC) { rC0 += KGT(hC0, lC0); rC1 += KGT(hC1, lC1);
                      rC2 += KGT(hC2, lC2); rC3 += KGT(hC3, lC3); }
            if (gD) { rD0 += KGT(hD0, lD0); rD1 += KGT(hD1, lD1);
                      rD2 += KGT(hD2, lD2); rD3 += KGT(hD3, lD3); }
        }
        #undef KGT
        #undef LKEY

        if (c       < (int)m2) atomicAdd(&rnk[c],        (unsigned)rA0);
        if (c + 128 < (int)m2) atomicAdd(&rnk[c + 128],  (unsigned)rA1);
        if (c + 256 < (int)m2) atomicAdd(&rnk[c + 256],  (unsigned)rA2);
        if (c + 384 < (int)m2) atomicAdd(&rnk[c + 384],  (unsigned)rA3);
        if (gB) {
            atomicAdd(&rnk[c + 512], (unsigned)rB0);
            if (c + 640 < (int)m2) atomicAdd(&rnk[c + 640], (unsigned)rB1);
            if (c + 768 < (int)m2) atomicAdd(&rnk[c + 768], (unsigned)rB2);
            if (c + 896 < (int)m2) atomicAdd(&rnk[c + 896], (unsigned)rB3);
        }
        if (gC) {
            atomicAdd(&rnk[c + 1024], (unsigned)rC0);
            if (c + 1152 < (int)m2) atomicAdd(&rnk[c + 1152], (unsigned)rC1);
            if (c + 1280 < (int)m2) atomicAdd(&rnk[c + 1280], (unsigned)rC2);
            if (c + 1408 < (int)m2) atomicAdd(&rnk[c + 1408], (unsigned)rC3);
        }
        if (gD) {
            atomicAdd(&rnk[c + 1536], (unsigned)rD0);
            if (c + 1664 < (int)m2) atomicAdd(&rnk[c + 1664], (unsigned)rD1);
            if (c + 1792 < (int)m2) atomicAdd(&rnk[c + 1792], (unsigned)rD2);
            if (c + 1920 < (int)m2) atomicAdd(&rnk[c + 1920], (unsigned)rD3);
        }
    }
    __syncthreads();

    float wmax = im_info[b * 3 + 1] - 1.0f;
    float hmax = im_info[b * 3 + 0] - 1.0f;
    for (unsigned i = tid; i < m2; i += 512) {
        unsigned n = ~klo[i];
        unsigned r = rnk[i];
        bxg[(size_t)b * SORT2 + r] = decode_box(n, deltas, b, wmax, hmax);
    }
    if (tid == 0) { m2arr[b] = m2; okarr[b] = ok ? 1u : 0u; }
}

// --- Pass 5: suppression bit-matrix incl. DIAGONAL word (fully parallel) -----
// Block (b, t): rows [64t, 64t+64), words w in [t, 32). Bit j of word w:
// IoU(row, 64w+j) > 0.7. Backward words unwritten (never consumed).
__global__ __launch_bounds__(256) void mask_kernel(
        const float4* __restrict__ bxg,
        const unsigned* __restrict__ m2arr,
        const unsigned* __restrict__ okarr,
        unsigned long long* __restrict__ mask) {
    int b = blockIdx.x >> 5;
    int t = blockIdx.x & 31;
    if (!okarr[b]) return;
    unsigned m2 = m2arr[b];
    if ((unsigned)(t * 64) >= m2) return;
    __shared__ float4 sb[SORT2];   // 32 KB
    __shared__ float  sa[SORT2];   //  8 KB
    int tid = threadIdx.x;
    int mceil = (int)((m2 + 63u) & ~63u);
    for (int i = tid; i < mceil; i += 256) {
        float4 v = (i < (int)m2) ? bxg[(size_t)b * SORT2 + i]
                                 : make_float4(-3e9f, -3e9f, -3e9f, -3e9f);
        sb[i] = v;
        sa[i] = (v.z - v.x + 1.f) * (v.w - v.y + 1.f);
    }
    __syncthreads();
    int r = t * 64 + (tid >> 2);
    int q = tid & 3;
    float4 rb = sb[r];
    float  ra = sa[r];
    unsigned long long* mrow = mask + ((size_t)b * SORT2 + r) * NWORD;
    for (int w = t + q; w < NWORD; w += 4) {
        if (w * 64 >= mceil) break;
        unsigned long long bits = 0;
        #pragma unroll 4
        for (int jj = 0; jj < 64; ++jj) {
            int j = w * 64 + jj;
            bits |= ((unsigned long long)(iou_over(rb, ra, sb[j], sa[j]) ? 1 : 0)) << jj;
        }
        mrow[w] = bits;
    }
}

// --- Pass 6: greedy resolve — diag rows in registers, readlane broadcast -----
__global__ __launch_bounds__(64) void resolve_kernel(
        const float4* __restrict__ bxg,
        const unsigned long long* __restrict__ mask,
        const unsigned* __restrict__ m2arr,
        const unsigned* __restrict__ okarr,
        float* __restrict__ out,
        unsigned* __restrict__ need_full) {
    int b = blockIdx.x;
    int lane = threadIdx.x;
    if (!okarr[b]) { if (lane == 0) need_full[b] = 1u; return; }
    int m2 = (int)m2arr[b];
    __shared__ unsigned short kept_idx[POST_NMS];
    const float4* bx = bxg + (size_t)b * SORT2;
    const unsigned long long* mb = mask + (size_t)b * SORT2 * NWORD;
    // cross-chunk suppressed mask S: word w is (lane w accum) | (lane 32+w accum)
    unsigned long long S = 0;
    int w32 = lane & 31;
    bool hiHalf = lane >= 32;
    int nchunks = (m2 + 63) >> 6;
    // prefetch diag word for chunk 0: lane j holds row j's word 0
    unsigned long long dpre = mb[(size_t)lane * NWORD + 0];
    int nk = 0;
    for (int c = 0; c < nchunks && nk < POST_NMS; ++c) {
        int base = c * 64;
        int nvalid = min(64, m2 - base);
        unsigned long long d = dpre;
        if (c + 1 < nchunks)   // prefetch next chunk's diag (independent)
            dpre = mb[(size_t)(base + 64 + lane) * NWORD + (c + 1)];
        // live = ~(word c of S), via cheap scalar broadcasts
        unsigned wl0 = __builtin_amdgcn_readlane((unsigned)S, c);
        unsigned wh0 = __builtin_amdgcn_readlane((unsigned)(S >> 32), c);
        unsigned wl1 = __builtin_amdgcn_readlane((unsigned)S, c + 32);
        unsigned wh1 = __builtin_amdgcn_readlane((unsigned)(S >> 32), c + 32);
        unsigned long long Sc = (((unsigned long long)wh0 << 32) | wl0)
                              | (((unsigned long long)wh1 << 32) | wl1);
        unsigned long long live = ~Sc;
        if (nvalid < 64) live &= (1ull << nvalid) - 1ull;
        unsigned long long keptC = 0;
        while (live && nk < POST_NMS) {
            int il = (int)__ffsll((long long)live) - 1;     // uniform
            unsigned dlo = __builtin_amdgcn_readlane((unsigned)d, il);
            unsigned dhi = __builtin_amdgcn_readlane((unsigned)(d >> 32), il);
            unsigned long long drow = ((unsigned long long)dhi << 32) | dlo;
            live &= ~drow;
            live &= ~(1ull << il);
            if (lane == 0) kept_idx[nk] = (unsigned short)(base + il);
            keptC |= 1ull << il;
            ++nk;
        }
        // cross-chunk S update: 8 rows/round, parity-split (2 lanes per word),
        // 4 independent loads per lane -> one latency per round
        if (nk < POST_NMS && c + 1 < nchunks && keptC) {
            long long kc = (long long)keptC;
            while (kc) {
                int r0 = (int)__ffsll(kc) - 1; kc &= kc - 1;
                int r1 = (int)__ffsll(kc) - 1; kc &= kc - 1;
                int r2 = (int)__ffsll(kc) - 1; kc &= kc - 1;
                int r3 = (int)__ffsll(kc) - 1; kc &= kc - 1;
                int r4 = (int)__ffsll(kc) - 1; kc &= kc - 1;
                int r5 = (int)__ffsll(kc) - 1; kc &= kc - 1;
                int r6 = (int)__ffsll(kc) - 1; kc &= kc - 1;
                int r7 = (int)__ffsll(kc) - 1; kc &= kc - 1;
                int s0 = hiHalf ? r1 : r0;
                int s1 = hiHalf ? r3 : r2;
                int s2 = hiHalf ? r5 : r4;
                int s3 = hiHalf ? r7 : r6;
                unsigned long long a0 = 0, a1 = 0, a2 = 0, a3 = 0;
                if (s0 >= 0) a0 = mb[(size_t)(base + s0) * NWORD + w32];
                if (s1 >= 0) a1 = mb[(size_t)(base + s1) * NWORD + w32];
                if (s2 >= 0) a2 = mb[(size_t)(base + s2) * NWORD + w32];
                if (s3 >= 0) a3 = mb[(size_t)(base + s3) * NWORD + w32];
                S |= a0 | a1 | a2 | a3;
            }
        }
    }
    __syncthreads();
    if (lane == 0) need_full[b] = (nk < POST_NMS) ? 1u : 0u;
    for (int t = lane; t < nk; t += 64) {
        float4 kb = bx[kept_idx[t]];
        float* o = out + ((size_t)b * POST_NMS + t) * 5;
        o[0] = (float)b;
        o[1] = kb.x; o[2] = kb.y; o[3] = kb.z; o[4] = kb.w;
    }
    for (int t = nk + lane; t < POST_NMS; t += 64) {
        float* o = out + ((size_t)b * POST_NMS + t) * 5;
        o[0] = (float)b;
        o[1] = 0.f; o[2] = 0.f; o[3] = 0.f; o[4] = 0.f;
    }
}

// --- Legacy fused fast path (used only if workspace too small for masks) -----
__global__ __launch_bounds__(512) void topk_nms_kernel(
        const unsigned long long* __restrict__ cand,
        const unsigned* __restrict__ cntpad,
        const unsigned* __restrict__ tbin2,
        const float* __restrict__ deltas,
        const float* __restrict__ im_info,
        float* __restrict__ out,
        unsigned* __restrict__ need_full) {
    int b = blockIdx.x;
    __shared__ unsigned long long keys[SORT2];
    __shared__ float4 bx[SORT2];
    __shared__ float4 kept_s[POST_NMS];
    __shared__ float karea_s[POST_NMS];
    __shared__ unsigned lcnt;
    int tid = threadIdx.x;
    if (tid == 0) lcnt = 0;
    for (int i = tid; i < SORT2; i += 512) keys[i] = 0ULL;
    __syncthreads();
    unsigned m = cntpad[b << 5];
    if (m > CAP) m = CAP;
    unsigned t2 = tbin2[b];
    for (unsigned i = tid; i < m; i += 512) {
        unsigned long long k64 = cand[(size_t)b * CAP + i];
        if ((unsigned)(k64 >> 48) >= t2) {
            unsigned pos = atomicAdd(&lcnt, 1u);
            if (pos < SORT2) keys[pos] = k64;
        }
    }
    __syncthreads();
    unsigned raw2 = lcnt;
    bool ok = (raw2 <= SORT2);
    unsigned m2 = raw2 > SORT2 ? SORT2 : raw2;
    for (unsigned k = 2; k <= SORT2; k <<= 1) {
        for (unsigned j = k >> 1; j > 0; j >>= 1) {
            #pragma unroll
            for (int pp = 0; pp < 2; ++pp) {
                unsigned p = (unsigned)tid + (unsigned)pp * 512u;
                unsigned i = ((p & ~(j - 1)) << 1) | (p & (j - 1));
                unsigned ixj = i | j;
                unsigned long long x = keys[i], y = keys[ixj];
                bool desc = ((i & k) == 0);
                if (desc ? (x < y) : (x > y)) { keys[i] = y; keys[ixj] = x; }
            }
            __syncthreads();
        }
    }
    float wmax = im_info[b * 3 + 1] - 1.0f;
    float hmax = im_info[b * 3 + 0] - 1.0f;
    for (unsigned i = tid; i < m2; i += 512) {
        unsigned n = ~(unsigned)(keys[i] & 0xFFFFFFFFull);
        bx[i] = decode_box(n, deltas, b, wmax, hmax);
    }
    __syncthreads();
    if (tid >= 64) return;
    int lane = tid;
    if (!ok) { if (lane == 0) need_full[b] = 1u; return; }
    int nk = 0;
    for (int i = 0; i < (int)m2 && nk < POST_NMS; ++i) {
        float4 cur = bx[i];
        float ca = (cur.z - cur.x + 1.f) * (cur.w - cur.y + 1.f);
        bool sup = false;
        for (int s = lane; s < nk; s += 64)
            sup |= iou_over(kept_s[s], karea_s[s], cur, ca);
        if (!__any(sup)) {
            if (lane == 0) {
                kept_s[nk] = cur; karea_s[nk] = ca;
                float* o = out + ((size_t)b * POST_NMS + nk) * 5;
                o[0] = (float)b;
                o[1] = cur.x; o[2] = cur.y; o[3] = cur.z; o[4] = cur.w;
            }
            ++nk;
        }
    }
    if (lane == 0) need_full[b] = (nk < POST_NMS) ? 1u : 0u;
    for (int t = nk + lane; t < POST_NMS; t += 64) {
        float* o = out + ((size_t)b * POST_NMS + t) * 5;
        o[0] = (float)b;
        o[1] = 0.f; o[2] = 0.f; o[3] = 0.f; o[4] = 0.f;
    }
}

// --- Fallback A: full 8192 bitonic sort + decode (gated, normally no-op) -----
__global__ __launch_bounds__(512) void fb_sort_kernel(
        const unsigned long long* __restrict__ cand,
        const unsigned* __restrict__ cntpad,
        const unsigned* __restrict__ need_full,
        const float* __restrict__ deltas,
        const float* __restrict__ im_info,
        float4* __restrict__ boxes) {
    int b = blockIdx.x;
    if (!need_full[b]) return;
    __shared__ unsigned long long keys[CAP];
    unsigned m = cntpad[b << 5];
    if (m > CAP) m = CAP;
    for (int i = threadIdx.x; i < CAP; i += 512)
        keys[i] = (i < (int)m) ? cand[(size_t)b * CAP + i] : 0ULL;
    __syncthreads();
    for (unsigned k = 2; k <= CAP; k <<= 1) {
        for (unsigned j = k >> 1; j > 0; j >>= 1) {
            #pragma unroll
            for (int pp = 0; pp < 8; ++pp) {
                unsigned p = (unsigned)threadIdx.x + (unsigned)pp * 512u;
                unsigned i = ((p & ~(j - 1)) << 1) | (p & (j - 1));
                unsigned ixj = i | j;
                unsigned long long x = keys[i], y = keys[ixj];
                bool desc = ((i & k) == 0);
                if (desc ? (x < y) : (x > y)) { keys[i] = y; keys[ixj] = x; }
            }
            __syncthreads();
        }
    }
    float wmax = im_info[b * 3 + 1] - 1.0f;
    float hmax = im_info[b * 3 + 0] - 1.0f;
    for (int i = threadIdx.x; i < PRE_NMS; i += 512) {
        unsigned n = ~(unsigned)(keys[i] & 0xFFFFFFFFull);
        float4 box = make_float4(0.f, 0.f, 0.f, 0.f);
        if (n < N_ANCH) box = decode_box(n, deltas, b, wmax, hmax);
        boxes[(size_t)b * PRE_NMS + i] = box;
    }
}

// --- Fallback B: full NMS over 6000 (gated, normally no-op) ------------------
__global__ __launch_bounds__(64) void fb_nms_kernel(const float4* __restrict__ boxes,
                                                    const unsigned* __restrict__ need_full,
                                                    float* __restrict__ out) {
    int b = blockIdx.x;
    if (!need_full[b]) return;
    int lane = threadIdx.x;
    __shared__ float4 cbuf[64];
    __shared__ float4 kept[POST_NMS];
    __shared__ float karea[POST_NMS];
    const float4* bb = boxes + (size_t)b * PRE_NMS;
    int nk = 0;
    for (int base = 0; base < PRE_NMS && nk < POST_NMS; base += 64) {
        if (base + lane < PRE_NMS) cbuf[lane] = bb[base + lane];
        __syncthreads();
        int lim = min(64, PRE_NMS - base);
        for (int jj = 0; jj < lim; ++jj) {
            float4 cur = cbuf[jj];
            float ca = (cur.z - cur.x + 1.f) * (cur.w - cur.y + 1.f);
            bool sup = false;
            for (int s = lane; s < nk; s += 64)
                sup |= iou_over(kept[s], karea[s], cur, ca);
            if (!__any(sup)) {
                if (lane == 0) {
                    kept[nk] = cur; karea[nk] = ca;
                    float* o = out + ((size_t)b * POST_NMS + nk) * 5;
                    o[0] = (float)b;
                    o[1] = cur.x; o[2] = cur.y; o[3] = cur.z; o[4] = cur.w;
                }
                ++nk;
                if (nk >= POST_NMS) break;
            }
        }
        __syncthreads();
    }
    for (int t = nk + lane; t < POST_NMS; t += 64) {
        float* o = out + ((size_t)b * POST_NMS + t) * 5;
        o[0] = (float)b;
        o[1] = 0.f; o[2] = 0.f; o[3] = 0.f; o[4] = 0.f;
    }
}

extern "C" void kernel_launch(void* const* d_in, const int* in_sizes, int n_in,
                              void* d_out, int out_size, void* d_ws, size_t ws_size,
                              hipStream_t stream) {
    const float* scores  = (const float*)d_in[0];
    const float* deltas  = (const float*)d_in[1];
    const float* im_info = (const float*)d_in[2];
    float* out = (float*)d_out;

    unsigned* histA   = (unsigned*)d_ws;                  // 16*256
    unsigned* histB   = histA + BATCH * 256;              // 16*256
    unsigned* cntpad  = histB + BATCH * 256;              // 16*32
    unsigned* d8      = cntpad + BATCH * 32;              // 16
    unsigned* aboveA  = d8 + BATCH;                       // 16
    unsigned* tbin    = aboveA + BATCH;                   // 16
    unsigned* tbin2   = tbin + BATCH;                     // 16
    unsigned* need_fl = tbin2 + BATCH;                    // 16
    unsigned* m2arr   = need_fl + BATCH;                  // 16
    unsigned* okarr   = m2arr + BATCH;                    // 16
    size_t off = (char*)(okarr + BATCH) - (char*)d_ws;
    off = (off + 255) & ~(size_t)255;
    unsigned long long* cand = (unsigned long long*)((char*)d_ws + off);
    off += (size_t)BATCH * CAP * 8;                       // 1 MB
    off = (off + 255) & ~(size_t)255;
    float4* boxes_fb = (float4*)((char*)d_ws + off);      // 1.5 MB (fallback)
    off += (size_t)BATCH * PRE_NMS * 16;
    off = (off + 255) & ~(size_t)255;
    float4* bxg = (float4*)((char*)d_ws + off);           // 512 KB
    off += (size_t)BATCH * SORT2 * 16;
    off = (off + 255) & ~(size_t)255;
    unsigned long long* mask = (unsigned long long*)((char*)d_ws + off); // 8 MB
    size_t need = off + (size_t)BATCH * SORT2 * NWORD * 8;

    const int nblk = BATCH * BPB;   // 1296
    init_kernel   <<<ZERO_WORDS / 256, 256, 0, stream>>>((unsigned*)d_ws);
    histA_kernel  <<<nblk, 256, 0, stream>>>(scores, histA);
    scanA_kernel  <<<BATCH, 256, 0, stream>>>(histA, d8, aboveA);
    histB_kernel  <<<nblk, 256, 0, stream>>>(scores, d8, histB);
    scanB_kernel  <<<BATCH, 256, 0, stream>>>(histB, d8, aboveA, tbin, tbin2);
    compact_kernel<<<nblk, 256, 0, stream>>>(scores, tbin, cntpad, cand);

    if (ws_size >= need) {
        sort_kernel   <<<BATCH, 512, 0, stream>>>(cand, cntpad, tbin2, deltas, im_info,
                                                  bxg, m2arr, okarr);
        mask_kernel   <<<BATCH * 32, 256, 0, stream>>>(bxg, m2arr, okarr, mask);
        resolve_kernel<<<BATCH, 64, 0, stream>>>(bxg, mask, m2arr, okarr, out, need_fl);
    } else {
        topk_nms_kernel<<<BATCH, 512, 0, stream>>>(cand, cntpad, tbin2, deltas, im_info,
                                                   out, need_fl);
    }
    fb_sort_kernel<<<BATCH, 512, 0, stream>>>(cand, cntpad, need_fl, deltas, im_info, boxes_fb);
    fb_nms_kernel <<<BATCH, 64, 0, stream>>>(boxes_fb, need_fl, out);
}

// Round 8
// 163.466 us; speedup vs baseline: 1.8082x; 1.8082x over previous
//
#include <hip/hip_runtime.h>
#include <stdint.h>

// Problem constants (fixed by setup_inputs: B=16, A=9, H=W=192)
#define A_NUM    9
#define W_FEAT   192
#define H_FEAT   192
#define K_FEAT   (W_FEAT * H_FEAT)     // 36864 positions
#define N_ANCH   (K_FEAT * A_NUM)      // 331776 anchors per batch
#define BATCH    16
#define PRE_NMS  6000
#define POST_NMS 300
#define CAP      8192                  // full candidate buffer (above tbin)
#define CHUNK    4096                  // elements per block for hist/compact
#define BPB      (N_ANCH / CHUNK)      // 81 blocks per batch
#define CPA      (K_FEAT / CHUNK)      // 9 chunks per anchor-plane
#define SBUF_CAP 1024                  // per-block candidate staging (mean ~91)
#define T2TGT    700                   // fast-path candidate target
#define SORT2    2048                  // fast-path sort size
#define NWORD    (SORT2 / 64)          // 32 mask words per row
#define ZERO_WORDS (2 * BATCH * 256 + BATCH * 32)   // histA + histB + cntpad

typedef unsigned long long u64;

// py-faster-rcnn standard anchors (base 16, ratios .5/1/2, scales 8/16/32)
__constant__ float c_anchors[A_NUM][4] = {
    { -84.f,  -40.f,  99.f,  55.f},
    {-176.f,  -88.f, 191.f, 103.f},
    {-360.f, -184.f, 375.f, 199.f},
    { -56.f,  -56.f,  71.f,  71.f},
    {-120.f, -120.f, 135.f, 135.f},
    {-248.f, -248.f, 263.f, 263.f},
    { -36.f,  -80.f,  51.f,  95.f},
    { -80.f, -168.f,  95.f, 183.f},
    {-168.f, -344.f, 183.f, 359.f},
};

__device__ __forceinline__ unsigned key_bits(float s) {
    unsigned ub = __float_as_uint(s);
    return (ub & 0x80000000u) ? ~ub : (ub | 0x80000000u);
}

__device__ __forceinline__ const float* chunk_ptr(const float* scores, int blk,
                                                  int& b, int& a, int& koff) {
    b = blk / BPB;
    int chunk = blk - b * BPB;
    a = chunk / CPA;
    koff = (chunk - a * CPA) * CHUNK;
    return scores + ((size_t)(b * 2 * A_NUM + A_NUM + a)) * K_FEAT + koff;
}

// ballot-aggregated LDS histogram add: one atomic per distinct bin per wave
__device__ __forceinline__ void hist_add(unsigned* lh, unsigned bin) {
    unsigned long long peers = __ballot(1);
    #pragma unroll
    for (int bit = 0; bit < 8; ++bit) {
        unsigned long long vote = __ballot((bin >> bit) & 1);
        peers &= ((bin >> bit) & 1) ? vote : ~vote;
    }
    int lane = threadIdx.x & 63;
    if (lane == (int)(__ffsll((long long)peers) - 1))
        atomicAdd(&lh[bin], (unsigned)__popcll(peers));
}

__device__ __forceinline__ float4 decode_box(unsigned n, const float* __restrict__ deltas,
                                             int b, float wmax, float hmax) {
    unsigned kk = n / A_NUM, a = n - kk * A_NUM;
    unsigned hh = kk / W_FEAT, ww = kk - hh * W_FEAT;
    size_t dbase = ((size_t)(b * 4 * A_NUM + 4 * a)) * K_FEAT + kk;
    float dx = deltas[dbase];
    float dy = deltas[dbase + (size_t)K_FEAT];
    float dw = deltas[dbase + (size_t)2 * K_FEAT];
    float dh = deltas[dbase + (size_t)3 * K_FEAT];
    float ax1 = c_anchors[a][0] + ww * 16.0f;
    float ay1 = c_anchors[a][1] + hh * 16.0f;
    float ax2 = c_anchors[a][2] + ww * 16.0f;
    float ay2 = c_anchors[a][3] + hh * 16.0f;
    float waf = ax2 - ax1 + 1.0f, haf = ay2 - ay1 + 1.0f;
    float cx = ax1 + 0.5f * waf, cy = ay1 + 0.5f * haf;
    float pcx = dx * waf + cx, pcy = dy * haf + cy;
    float pw = expf(dw) * waf, ph = expf(dh) * haf;
    float4 box;
    box.x = fminf(fmaxf(pcx - 0.5f * pw, 0.f), wmax);
    box.y = fminf(fmaxf(pcy - 0.5f * ph, 0.f), hmax);
    box.z = fminf(fmaxf(pcx + 0.5f * pw, 0.f), wmax);
    box.w = fminf(fmaxf(pcy + 0.5f * ph, 0.f), hmax);
    return box;
}

// IoU(a, c) > 0.7 — identical algebra in every consumer (bit-identical decisions)
__device__ __forceinline__ bool iou_over(float4 a, float aa, float4 c, float ca) {
    float xx1 = fmaxf(a.x, c.x), yy1 = fmaxf(a.y, c.y);
    float xx2 = fminf(a.z, c.z), yy2 = fminf(a.w, c.w);
    float iw = fmaxf(xx2 - xx1 + 1.f, 0.f);
    float ih = fmaxf(yy2 - yy1 + 1.f, 0.f);
    float inter = iw * ih;
    return inter > 0.7f * (aa + ca - inter);
}

__device__ __forceinline__ u64 shflxor64(u64 v, int j) {
    unsigned lo = (unsigned)v, hi = (unsigned)(v >> 32);
    lo = __shfl_xor(lo, j, 64);
    hi = __shfl_xor(hi, j, 64);
    return ((u64)hi << 32) | lo;
}

// --- Pass 0: zero hist/cnt workspace (replaces pathological hipMemsetAsync) --
__global__ __launch_bounds__(256) void init_kernel(unsigned* __restrict__ p) {
    p[blockIdx.x * 256 + threadIdx.x] = 0u;
}

// --- Pass 1a: per-batch 256-bin histogram of top-8 key bits ------------------
__global__ __launch_bounds__(256) void histA_kernel(const float* __restrict__ scores,
                                                    unsigned* __restrict__ histA) {
    __shared__ unsigned lh[256];
    int tid = threadIdx.x;
    lh[tid] = 0;
    __syncthreads();
    int b, a, koff;
    const float* p = chunk_ptr(scores, blockIdx.x, b, a, koff);
    const float4* p4 = (const float4*)p;
    #pragma unroll
    for (int it = 0; it < CHUNK / 1024; ++it) {
        float4 v = p4[it * 256 + tid];
        hist_add(lh, key_bits(v.x) >> 24);
        hist_add(lh, key_bits(v.y) >> 24);
        hist_add(lh, key_bits(v.z) >> 24);
        hist_add(lh, key_bits(v.w) >> 24);
    }
    __syncthreads();
    if (lh[tid]) atomicAdd(&histA[b * 256 + tid], lh[tid]);
}

// --- Pass 1b: top-8 threshold digit ------------------------------------------
__global__ void scanA_kernel(const unsigned* __restrict__ histA,
                             unsigned* __restrict__ d8,
                             unsigned* __restrict__ aboveA) {
    int b = blockIdx.x;
    __shared__ unsigned h[256];
    h[threadIdx.x] = histA[b * 256 + threadIdx.x];
    __syncthreads();
    if (threadIdx.x == 0) {
        unsigned acc = 0; int d = 0;
        for (int i = 255; i >= 0; --i) {
            unsigned v = h[i];
            if (acc + v >= PRE_NMS) { d = i; break; }
            acc += v;
        }
        d8[b] = (unsigned)d;
        aboveA[b] = acc;
    }
}

// --- Pass 2a: refine next 8 bits among values with top-8 == d8 ---------------
__global__ __launch_bounds__(256) void histB_kernel(const float* __restrict__ scores,
                                                    const unsigned* __restrict__ d8,
                                                    unsigned* __restrict__ histB) {
    __shared__ unsigned lh[256];
    int tid = threadIdx.x;
    lh[tid] = 0;
    __syncthreads();
    int b, a, koff;
    const float* p = chunk_ptr(scores, blockIdx.x, b, a, koff);
    unsigned d = d8[b];
    const float4* p4 = (const float4*)p;
    #pragma unroll
    for (int it = 0; it < CHUNK / 1024; ++it) {
        float4 v = p4[it * 256 + tid];
        unsigned u0 = key_bits(v.x), u1 = key_bits(v.y);
        unsigned u2 = key_bits(v.z), u3 = key_bits(v.w);
        if ((u0 >> 24) == d) hist_add(lh, (u0 >> 16) & 0xFF);
        if ((u1 >> 24) == d) hist_add(lh, (u1 >> 16) & 0xFF);
        if ((u2 >> 24) == d) hist_add(lh, (u2 >> 16) & 0xFF);
        if ((u3 >> 24) == d) hist_add(lh, (u3 >> 16) & 0xFF);
    }
    __syncthreads();
    if (lh[tid]) atomicAdd(&histB[b * 256 + tid], lh[tid]);
}

// --- Pass 2b: final 16-bit thresholds (6000-target and fast 700-target) ------
__global__ void scanB_kernel(const unsigned* __restrict__ histB,
                             const unsigned* __restrict__ d8,
                             const unsigned* __restrict__ aboveA,
                             unsigned* __restrict__ tbin,
                             unsigned* __restrict__ tbin2) {
    int b = blockIdx.x;
    __shared__ unsigned h[256];
    h[threadIdx.x] = histB[b * 256 + threadIdx.x];
    __syncthreads();
    if (threadIdx.x == 0) {
        unsigned dd = d8[b];
        unsigned acc = aboveA[b];
        unsigned t2 = 0; bool t2set = false;
        if (acc >= T2TGT) { t2 = (dd + 1) << 8; t2set = true; }
        int d = 0;
        for (int i = 255; i >= 0; --i) {
            unsigned v = h[i];
            if (!t2set && acc + v >= T2TGT) { t2 = (dd << 8) | (unsigned)i; t2set = true; }
            if (acc + v >= PRE_NMS) { d = i; break; }
            acc += v;
        }
        tbin[b] = (dd << 8) | (unsigned)d;
        tbin2[b] = t2set ? t2 : ((dd << 8) | (unsigned)d);
    }
}

// --- Pass 3: compact candidates >= tbin (LDS staged, 1 global atomic/block) --
__global__ __launch_bounds__(256) void compact_kernel(
        const float* __restrict__ scores,
        const unsigned* __restrict__ tbin,
        unsigned* __restrict__ cntpad,
        u64* __restrict__ cand) {
    __shared__ u64 sbuf[SBUF_CAP];
    __shared__ unsigned scount, sbase;
    int tid = threadIdx.x;
    if (tid == 0) scount = 0;
    __syncthreads();
    int b, a, koff;
    const float* p = chunk_ptr(scores, blockIdx.x, b, a, koff);
    unsigned t = tbin[b];
    const float4* p4 = (const float4*)p;
    #pragma unroll
    for (int it = 0; it < CHUNK / 1024; ++it) {
        float4 v = p4[it * 256 + tid];
        unsigned e0 = (unsigned)(koff + (it * 256 + tid) * 4);
        float vv[4] = {v.x, v.y, v.z, v.w};
        #pragma unroll
        for (int j = 0; j < 4; ++j) {
            unsigned ub = key_bits(vv[j]);
            if ((ub >> 16) >= t) {
                unsigned n = (e0 + j) * A_NUM + a;
                unsigned pos = atomicAdd(&scount, 1u);
                if (pos < SBUF_CAP)
                    sbuf[pos] = ((u64)ub << 32) | (unsigned)(~n);
            }
        }
    }
    __syncthreads();
    unsigned c = scount < SBUF_CAP ? scount : SBUF_CAP;
    if (tid == 0) sbase = atomicAdd(&cntpad[b << 5], c);
    __syncthreads();
    unsigned gb = sbase;
    for (unsigned i = tid; i < c; i += 256) {
        unsigned pos = gb + i;
        if (pos < CAP) cand[(size_t)b * CAP + pos] = sbuf[i];
    }
}

// --- Pass 4: filter >= tbin2, HYBRID register/LDS bitonic sort 2048, decode --
// 512 threads x 4 elems: wave w owns segment [256w, 256w+256), lane l holds
// indices 256w + 64p + l. Phases: j<=32 shfl_xor; j in {64,128} intra-thread;
// j>=256 LDS. Only 6 LDS phases + 4 register sessions (~10 barriers vs 66).
#define KEYRD(I)  ((((u64)khi[(I)]) << 32) | klo[(I)])
#define KEYWR(I, V) do { khi[(I)] = (unsigned)((V) >> 32); klo[(I)] = (unsigned)(V); } while (0)

#define CE_SHFL(E, J, DESC) do { \
    u64 _v = shflxor64((E), (J)); \
    bool _kmax = ((DESC) == ((l & (J)) == 0)); \
    (E) = _kmax ? ((E) > _v ? (E) : _v) : ((E) < _v ? (E) : _v); \
} while (0)

#define CE_PAIR(A, B, DESC) do { \
    u64 _mx = (A) > (B) ? (A) : (B); \
    u64 _mn = (A) > (B) ? (B) : (A); \
    if (DESC) { (A) = _mx; (B) = _mn; } else { (A) = _mn; (B) = _mx; } \
} while (0)

__global__ __launch_bounds__(512) void sort_kernel(
        const u64* __restrict__ cand,
        const unsigned* __restrict__ cntpad,
        const unsigned* __restrict__ tbin2,
        const float* __restrict__ deltas,
        const float* __restrict__ im_info,
        float4* __restrict__ bxg,
        unsigned* __restrict__ m2arr,
        unsigned* __restrict__ okarr) {
    int b = blockIdx.x;
    __shared__ unsigned khi[SORT2];   // 8 KB
    __shared__ unsigned klo[SORT2];   // 8 KB
    __shared__ unsigned lcnt;
    int tid = threadIdx.x;
    int l = tid & 63, w = tid >> 6;
    if (tid == 0) lcnt = 0;
    for (int i = tid; i < SORT2; i += 512) { khi[i] = 0u; klo[i] = 0u; }
    __syncthreads();

    // filter with wave-aggregated ballot compaction (order fixed by sort)
    unsigned m = cntpad[b << 5];
    if (m > CAP) m = CAP;
    unsigned t2 = tbin2[b];
    unsigned mpad = (m + 511u) & ~511u;
    for (unsigned i = tid; i < mpad; i += 512) {
        bool pred = false; u64 k64 = 0;
        if (i < m) {
            k64 = cand[(size_t)b * CAP + i];
            pred = ((unsigned)(k64 >> 48) >= t2);
        }
        u64 bal = __ballot(pred);
        unsigned base = 0;
        if (l == 0 && bal) base = atomicAdd(&lcnt, (unsigned)__popcll(bal));
        base = __shfl(base, 0);
        if (pred) {
            unsigned pos = base + (unsigned)__popcll(bal & ((1ull << l) - 1ull));
            if (pos < SORT2) KEYWR(pos, k64);
        }
    }
    __syncthreads();
    unsigned raw2 = lcnt;
    bool ok = (raw2 <= SORT2);
    unsigned m2 = raw2 > SORT2 ? SORT2 : raw2;

    {
        int seg = w << 8;
        u64 e0 = KEYRD(seg + l);
        u64 e1 = KEYRD(seg + 64 + l);
        u64 e2 = KEYRD(seg + 128 + l);
        u64 e3 = KEYRD(seg + 192 + l);

        // stages k=2..32 (desc = lane bit, all phases shfl)
        #pragma unroll
        for (int k = 2; k <= 32; k <<= 1) {
            bool d = ((l & k) == 0);
            #pragma unroll
            for (int j = k >> 1; j >= 1; j >>= 1) {
                CE_SHFL(e0, j, d); CE_SHFL(e1, j, d);
                CE_SHFL(e2, j, d); CE_SHFL(e3, j, d);
            }
        }
        // stage k=64: desc by p&1 (e0,e2: desc; e1,e3: asc)
        #pragma unroll
        for (int j = 32; j >= 1; j >>= 1) {
            CE_SHFL(e0, j, true);  CE_SHFL(e1, j, false);
            CE_SHFL(e2, j, true);  CE_SHFL(e3, j, false);
        }
        // stage k=128: desc by p&2 (e0,e1: desc; e2,e3: asc)
        CE_PAIR(e0, e1, true); CE_PAIR(e2, e3, false);     // j=64
        #pragma unroll
        for (int j = 32; j >= 1; j >>= 1) {
            CE_SHFL(e0, j, true);  CE_SHFL(e1, j, true);
            CE_SHFL(e2, j, false); CE_SHFL(e3, j, false);
        }
        // stage k=256: desc by w&1 (wave-uniform)
        {
            bool d = ((w & 1) == 0);
            CE_PAIR(e0, e2, d); CE_PAIR(e1, e3, d);        // j=128
            CE_PAIR(e0, e1, d); CE_PAIR(e2, e3, d);        // j=64
            #pragma unroll
            for (int j = 32; j >= 1; j >>= 1) {
                CE_SHFL(e0, j, d); CE_SHFL(e1, j, d);
                CE_SHFL(e2, j, d); CE_SHFL(e3, j, d);
            }
        }
        KEYWR(seg + l, e0); KEYWR(seg + 64 + l, e1);
        KEYWR(seg + 128 + l, e2); KEYWR(seg + 192 + l, e3);
    }
    __syncthreads();

    // LDS phase (j >= 256) + register tail (j <= 128) per stage k >= 512
    #define LDS_PHASE(K, J) do { \
        _Pragma("unroll") \
        for (int pp = 0; pp < 2; ++pp) { \
            unsigned p = (unsigned)tid + (unsigned)pp * 512u; \
            unsigned i = ((p & ~((unsigned)(J) - 1u)) << 1) | (p & ((unsigned)(J) - 1u)); \
            unsigned ixj = i | (unsigned)(J); \
            u64 x = KEYRD(i), y = KEYRD(ixj); \
            bool dsc = ((i & (unsigned)(K)) == 0u); \
            if (dsc ? (x < y) : (x > y)) { KEYWR(i, y); KEYWR(ixj, x); } \
        } \
        __syncthreads(); \
    } while (0)

    #define REG_TAIL(D) do { \
        int seg = w << 8; \
        bool d = (D); \
        u64 e0 = KEYRD(seg + l); \
        u64 e1 = KEYRD(seg + 64 + l); \
        u64 e2 = KEYRD(seg + 128 + l); \
        u64 e3 = KEYRD(seg + 192 + l); \
        CE_PAIR(e0, e2, d); CE_PAIR(e1, e3, d); \
        CE_PAIR(e0, e1, d); CE_PAIR(e2, e3, d); \
        _Pragma("unroll") \
        for (int j = 32; j >= 1; j >>= 1) { \
            CE_SHFL(e0, j, d); CE_SHFL(e1, j, d); \
            CE_SHFL(e2, j, d); CE_SHFL(e3, j, d); \
        } \
        KEYWR(seg + l, e0); KEYWR(seg + 64 + l, e1); \
        KEYWR(seg + 128 + l, e2); KEYWR(seg + 192 + l, e3); \
        __syncthreads(); \
    } while (0)

    LDS_PHASE(512, 256);                 REG_TAIL(((w & 2) == 0));
    LDS_PHASE(1024, 512); LDS_PHASE(1024, 256);  REG_TAIL(((w & 4) == 0));
    LDS_PHASE(2048, 1024); LDS_PHASE(2048, 512); LDS_PHASE(2048, 256);
    REG_TAIL(true);

    float wmax = im_info[b * 3 + 1] - 1.0f;
    float hmax = im_info[b * 3 + 0] - 1.0f;
    for (unsigned i = tid; i < m2; i += 512) {
        unsigned n = ~klo[i];
        bxg[(size_t)b * SORT2 + i] = decode_box(n, deltas, b, wmax, hmax);
    }
    if (tid == 0) { m2arr[b] = m2; okarr[b] = ok ? 1u : 0u; }
}

// --- Pass 5: suppression bit-matrix incl. DIAGONAL word (fully parallel) -----
__global__ __launch_bounds__(256) void mask_kernel(
        const float4* __restrict__ bxg,
        const unsigned* __restrict__ m2arr,
        const unsigned* __restrict__ okarr,
        u64* __restrict__ mask) {
    int b = blockIdx.x >> 5;
    int t = blockIdx.x & 31;
    if (!okarr[b]) return;
    unsigned m2 = m2arr[b];
    if ((unsigned)(t * 64) >= m2) return;
    __shared__ float4 sb[SORT2];   // 32 KB
    __shared__ float  sa[SORT2];   //  8 KB
    int tid = threadIdx.x;
    int mceil = (int)((m2 + 63u) & ~63u);
    for (int i = tid; i < mceil; i += 256) {
        float4 v = (i < (int)m2) ? bxg[(size_t)b * SORT2 + i]
                                 : make_float4(-3e9f, -3e9f, -3e9f, -3e9f);
        sb[i] = v;
        sa[i] = (v.z - v.x + 1.f) * (v.w - v.y + 1.f);
    }
    __syncthreads();
    int r = t * 64 + (tid >> 2);
    int q = tid & 3;
    float4 rb = sb[r];
    float  ra = sa[r];
    u64* mrow = mask + ((size_t)b * SORT2 + r) * NWORD;
    for (int w = t + q; w < NWORD; w += 4) {
        if (w * 64 >= mceil) break;
        u64 bits = 0;
        #pragma unroll 4
        for (int jj = 0; jj < 64; ++jj) {
            int j = w * 64 + jj;
            bits |= ((u64)(iou_over(rb, ra, sb[j], sa[j]) ? 1 : 0)) << jj;
        }
        mrow[w] = bits;
    }
}

// --- Pass 6: greedy resolve — diag rows in registers, readlane broadcast -----
__global__ __launch_bounds__(64) void resolve_kernel(
        const float4* __restrict__ bxg,
        const u64* __restrict__ mask,
        const unsigned* __restrict__ m2arr,
        const unsigned* __restrict__ okarr,
        float* __restrict__ out,
        unsigned* __restrict__ need_full) {
    int b = blockIdx.x;
    int lane = threadIdx.x;
    if (!okarr[b]) { if (lane == 0) need_full[b] = 1u; return; }
    int m2 = (int)m2arr[b];
    __shared__ unsigned short kept_idx[POST_NMS];
    const float4* bx = bxg + (size_t)b * SORT2;
    const u64* mb = mask + (size_t)b * SORT2 * NWORD;
    u64 S = 0;
    int w32 = lane & 31;
    bool hiHalf = lane >= 32;
    int nchunks = (m2 + 63) >> 6;
    u64 dpre = mb[(size_t)lane * NWORD + 0];
    int nk = 0;
    for (int c = 0; c < nchunks && nk < POST_NMS; ++c) {
        int base = c * 64;
        int nvalid = min(64, m2 - base);
        u64 d = dpre;
        if (c + 1 < nchunks)
            dpre = mb[(size_t)(base + 64 + lane) * NWORD + (c + 1)];
        unsigned wl0 = __builtin_amdgcn_readlane((unsigned)S, c);
        unsigned wh0 = __builtin_amdgcn_readlane((unsigned)(S >> 32), c);
        unsigned wl1 = __builtin_amdgcn_readlane((unsigned)S, c + 32);
        unsigned wh1 = __builtin_amdgcn_readlane((unsigned)(S >> 32), c + 32);
        u64 Sc = (((u64)wh0 << 32) | wl0) | (((u64)wh1 << 32) | wl1);
        u64 live = ~Sc;
        if (nvalid < 64) live &= (1ull << nvalid) - 1ull;
        u64 keptC = 0;
        while (live && nk < POST_NMS) {
            int il = (int)__ffsll((long long)live) - 1;
            unsigned dlo = __builtin_amdgcn_readlane((unsigned)d, il);
            unsigned dhi = __builtin_amdgcn_readlane((unsigned)(d >> 32), il);
            u64 drow = ((u64)dhi << 32) | dlo;
            live &= ~drow;
            live &= ~(1ull << il);
            if (lane == 0) kept_idx[nk] = (unsigned short)(base + il);
            keptC |= 1ull << il;
            ++nk;
        }
        if (nk < POST_NMS && c + 1 < nchunks && keptC) {
            long long kc = (long long)keptC;
            while (kc) {
                int r0 = (int)__ffsll(kc) - 1; kc &= kc - 1;
                int r1 = (int)__ffsll(kc) - 1; kc &= kc - 1;
                int r2 = (int)__ffsll(kc) - 1; kc &= kc - 1;
                int r3 = (int)__ffsll(kc) - 1; kc &= kc - 1;
                int r4 = (int)__ffsll(kc) - 1; kc &= kc - 1;
                int r5 = (int)__ffsll(kc) - 1; kc &= kc - 1;
                int r6 = (int)__ffsll(kc) - 1; kc &= kc - 1;
                int r7 = (int)__ffsll(kc) - 1; kc &= kc - 1;
                int s0 = hiHalf ? r1 : r0;
                int s1 = hiHalf ? r3 : r2;
                int s2 = hiHalf ? r5 : r4;
                int s3 = hiHalf ? r7 : r6;
                u64 a0 = 0, a1 = 0, a2 = 0, a3 = 0;
                if (s0 >= 0) a0 = mb[(size_t)(base + s0) * NWORD + w32];
                if (s1 >= 0) a1 = mb[(size_t)(base + s1) * NWORD + w32];
                if (s2 >= 0) a2 = mb[(size_t)(base + s2) * NWORD + w32];
                if (s3 >= 0) a3 = mb[(size_t)(base + s3) * NWORD + w32];
                S |= a0 | a1 | a2 | a3;
            }
        }
    }
    __syncthreads();
    if (lane == 0) need_full[b] = (nk < POST_NMS) ? 1u : 0u;
    for (int t = lane; t < nk; t += 64) {
        float4 kb = bx[kept_idx[t]];
        float* o = out + ((size_t)b * POST_NMS + t) * 5;
        o[0] = (float)b;
        o[1] = kb.x; o[2] = kb.y; o[3] = kb.z; o[4] = kb.w;
    }
    for (int t = nk + lane; t < POST_NMS; t += 64) {
        float* o = out + ((size_t)b * POST_NMS + t) * 5;
        o[0] = (float)b;
        o[1] = 0.f; o[2] = 0.f; o[3] = 0.f; o[4] = 0.f;
    }
}

// --- Legacy fused fast path (used only if workspace too small for masks) -----
__global__ __launch_bounds__(512) void topk_nms_kernel(
        const u64* __restrict__ cand,
        const unsigned* __restrict__ cntpad,
        const unsigned* __restrict__ tbin2,
        const float* __restrict__ deltas,
        const float* __restrict__ im_info,
        float* __restrict__ out,
        unsigned* __restrict__ need_full) {
    int b = blockIdx.x;
    __shared__ u64 keys[SORT2];
    __shared__ float4 bx[SORT2];
    __shared__ float4 kept_s[POST_NMS];
    __shared__ float karea_s[POST_NMS];
    __shared__ unsigned lcnt;
    int tid = threadIdx.x;
    if (tid == 0) lcnt = 0;
    for (int i = tid; i < SORT2; i += 512) keys[i] = 0ULL;
    __syncthreads();
    unsigned m = cntpad[b << 5];
    if (m > CAP) m = CAP;
    unsigned t2 = tbin2[b];
    for (unsigned i = tid; i < m; i += 512) {
        u64 k64 = cand[(size_t)b * CAP + i];
        if ((unsigned)(k64 >> 48) >= t2) {
            unsigned pos = atomicAdd(&lcnt, 1u);
            if (pos < SORT2) keys[pos] = k64;
        }
    }
    __syncthreads();
    unsigned raw2 = lcnt;
    bool ok = (raw2 <= SORT2);
    unsigned m2 = raw2 > SORT2 ? SORT2 : raw2;
    for (unsigned k = 2; k <= SORT2; k <<= 1) {
        for (unsigned j = k >> 1; j > 0; j >>= 1) {
            #pragma unroll
            for (int pp = 0; pp < 2; ++pp) {
                unsigned p = (unsigned)tid + (unsigned)pp * 512u;
                unsigned i = ((p & ~(j - 1)) << 1) | (p & (j - 1));
                unsigned ixj = i | j;
                u64 x = keys[i], y = keys[ixj];
                bool desc = ((i & k) == 0);
                if (desc ? (x < y) : (x > y)) { keys[i] = y; keys[ixj] = x; }
            }
            __syncthreads();
        }
    }
    float wmax = im_info[b * 3 + 1] - 1.0f;
    float hmax = im_info[b * 3 + 0] - 1.0f;
    for (unsigned i = tid; i < m2; i += 512) {
        unsigned n = ~(unsigned)(keys[i] & 0xFFFFFFFFull);
        bx[i] = decode_box(n, deltas, b, wmax, hmax);
    }
    __syncthreads();
    if (tid >= 64) return;
    int lane = tid;
    if (!ok) { if (lane == 0) need_full[b] = 1u; return; }
    int nk = 0;
    for (int i = 0; i < (int)m2 && nk < POST_NMS; ++i) {
        float4 cur = bx[i];
        float ca = (cur.z - cur.x + 1.f) * (cur.w - cur.y + 1.f);
        bool sup = false;
        for (int s = lane; s < nk; s += 64)
            sup |= iou_over(kept_s[s], karea_s[s], cur, ca);
        if (!__any(sup)) {
            if (lane == 0) {
                kept_s[nk] = cur; karea_s[nk] = ca;
                float* o = out + ((size_t)b * POST_NMS + nk) * 5;
                o[0] = (float)b;
                o[1] = cur.x; o[2] = cur.y; o[3] = cur.z; o[4] = cur.w;
            }
            ++nk;
        }
    }
    if (lane == 0) need_full[b] = (nk < POST_NMS) ? 1u : 0u;
    for (int t = nk + lane; t < POST_NMS; t += 64) {
        float* o = out + ((size_t)b * POST_NMS + t) * 5;
        o[0] = (float)b;
        o[1] = 0.f; o[2] = 0.f; o[3] = 0.f; o[4] = 0.f;
    }
}

// --- Fallback A: full 8192 bitonic sort + decode (gated, normally no-op) -----
__global__ __launch_bounds__(512) void fb_sort_kernel(
        const u64* __restrict__ cand,
        const unsigned* __restrict__ cntpad,
        const unsigned* __restrict__ need_full,
        const float* __restrict__ deltas,
        const float* __restrict__ im_info,
        float4* __restrict__ boxes) {
    int b = blockIdx.x;
    if (!need_full[b]) return;
    __shared__ u64 keys[CAP];
    unsigned m = cntpad[b << 5];
    if (m > CAP) m = CAP;
    for (int i = threadIdx.x; i < CAP; i += 512)
        keys[i] = (i < (int)m) ? cand[(size_t)b * CAP + i] : 0ULL;
    __syncthreads();
    for (unsigned k = 2; k <= CAP; k <<= 1) {
        for (unsigned j = k >> 1; j > 0; j >>= 1) {
            #pragma unroll
            for (int pp = 0; pp < 8; ++pp) {
                unsigned p = (unsigned)threadIdx.x + (unsigned)pp * 512u;
                unsigned i = ((p & ~(j - 1)) << 1) | (p & (j - 1));
                unsigned ixj = i | j;
                u64 x = keys[i], y = keys[ixj];
                bool desc = ((i & k) == 0);
                if (desc ? (x < y) : (x > y)) { keys[i] = y; keys[ixj] = x; }
            }
            __syncthreads();
        }
    }
    float wmax = im_info[b * 3 + 1] - 1.0f;
    float hmax = im_info[b * 3 + 0] - 1.0f;
    for (int i = threadIdx.x; i < PRE_NMS; i += 512) {
        unsigned n = ~(unsigned)(keys[i] & 0xFFFFFFFFull);
        float4 box = make_float4(0.f, 0.f, 0.f, 0.f);
        if (n < N_ANCH) box = decode_box(n, deltas, b, wmax, hmax);
        boxes[(size_t)b * PRE_NMS + i] = box;
    }
}

// --- Fallback B: full NMS over 6000 (gated, normally no-op) ------------------
__global__ __launch_bounds__(64) void fb_nms_kernel(const float4* __restrict__ boxes,
                                                    const unsigned* __restrict__ need_full,
                                                    float* __restrict__ out) {
    int b = blockIdx.x;
    if (!need_full[b]) return;
    int lane = threadIdx.x;
    __shared__ float4 cbuf[64];
    __shared__ float4 kept[POST_NMS];
    __shared__ float karea[POST_NMS];
    const float4* bb = boxes + (size_t)b * PRE_NMS;
    int nk = 0;
    for (int base = 0; base < PRE_NMS && nk < POST_NMS; base += 64) {
        if (base + lane < PRE_NMS) cbuf[lane] = bb[base + lane];
        __syncthreads();
        int lim = min(64, PRE_NMS - base);
        for (int jj = 0; jj < lim; ++jj) {
            float4 cur = cbuf[jj];
            float ca = (cur.z - cur.x + 1.f) * (cur.w - cur.y + 1.f);
            bool sup = false;
            for (int s = lane; s < nk; s += 64)
                sup |= iou_over(kept[s], karea[s], cur, ca);
            if (!__any(sup)) {
                if (lane == 0) {
                    kept[nk] = cur; karea[nk] = ca;
                    float* o = out + ((size_t)b * POST_NMS + nk) * 5;
                    o[0] = (float)b;
                    o[1] = cur.x; o[2] = cur.y; o[3] = cur.z; o[4] = cur.w;
                }
                ++nk;
                if (nk >= POST_NMS) break;
            }
        }
        __syncthreads();
    }
    for (int t = nk + lane; t < POST_NMS; t += 64) {
        float* o = out + ((size_t)b * POST_NMS + t) * 5;
        o[0] = (float)b;
        o[1] = 0.f; o[2] = 0.f; o[3] = 0.f; o[4] = 0.f;
    }
}

extern "C" void kernel_launch(void* const* d_in, const int* in_sizes, int n_in,
                              void* d_out, int out_size, void* d_ws, size_t ws_size,
                              hipStream_t stream) {
    const float* scores  = (const float*)d_in[0];
    const float* deltas  = (const float*)d_in[1];
    const float* im_info = (const float*)d_in[2];
    float* out = (float*)d_out;

    unsigned* histA   = (unsigned*)d_ws;                  // 16*256
    unsigned* histB   = histA + BATCH * 256;              // 16*256
    unsigned* cntpad  = histB + BATCH * 256;              // 16*32
    unsigned* d8      = cntpad + BATCH * 32;              // 16
    unsigned* aboveA  = d8 + BATCH;                       // 16
    unsigned* tbin    = aboveA + BATCH;                   // 16
    unsigned* tbin2   = tbin + BATCH;                     // 16
    unsigned* need_fl = tbin2 + BATCH;                    // 16
    unsigned* m2arr   = need_fl + BATCH;                  // 16
    unsigned* okarr   = m2arr + BATCH;                    // 16
    size_t off = (char*)(okarr + BATCH) - (char*)d_ws;
    off = (off + 255) & ~(size_t)255;
    u64* cand = (u64*)((char*)d_ws + off);
    off += (size_t)BATCH * CAP * 8;                       // 1 MB
    off = (off + 255) & ~(size_t)255;
    float4* boxes_fb = (float4*)((char*)d_ws + off);      // 1.5 MB (fallback)
    off += (size_t)BATCH * PRE_NMS * 16;
    off = (off + 255) & ~(size_t)255;
    float4* bxg = (float4*)((char*)d_ws + off);           // 512 KB
    off += (size_t)BATCH * SORT2 * 16;
    off = (off + 255) & ~(size_t)255;
    u64* mask = (u64*)((char*)d_ws + off);                // 8 MB
    size_t need = off + (size_t)BATCH * SORT2 * NWORD * 8;

    const int nblk = BATCH * BPB;   // 1296
    init_kernel   <<<ZERO_WORDS / 256, 256, 0, stream>>>((unsigned*)d_ws);
    histA_kernel  <<<nblk, 256, 0, stream>>>(scores, histA);
    scanA_kernel  <<<BATCH, 256, 0, stream>>>(histA, d8, aboveA);
    histB_kernel  <<<nblk, 256, 0, stream>>>(scores, d8, histB);
    scanB_kernel  <<<BATCH, 256, 0, stream>>>(histB, d8, aboveA, tbin, tbin2);
    compact_kernel<<<nblk, 256, 0, stream>>>(scores, tbin, cntpad, cand);

    if (ws_size >= need) {
        sort_kernel   <<<BATCH, 512, 0, stream>>>(cand, cntpad, tbin2, deltas, im_info,
                                                  bxg, m2arr, okarr);
        mask_kernel   <<<BATCH * 32, 256, 0, stream>>>(bxg, m2arr, okarr, mask);
        resolve_kernel<<<BATCH, 64, 0, stream>>>(bxg, mask, m2arr, okarr, out, need_fl);
    } else {
        topk_nms_kernel<<<BATCH, 512, 0, stream>>>(cand, cntpad, tbin2, deltas, im_info,
                                                   out, need_fl);
    }
    fb_sort_kernel<<<BATCH, 512, 0, stream>>>(cand, cntpad, need_fl, deltas, im_info, boxes_fb);
    fb_nms_kernel <<<BATCH, 64, 0, stream>>>(boxes_fb, need_fl, out);
}